// Round 1
// baseline (1327.583 us; speedup 1.0000x reference)
//
#include <hip/hip_runtime.h>
#include <math.h>

#define T 4
#define LL 3
#define C 256
#define DIN 20
#define NN 4096
#define EE 65536
#define AHD 4

// ---- workspace layout (4-byte word offsets) ----
#define W_OFF    0                    // int[N*T+1]
#define W_CURSOR 16640                // int[N*T]  (also hist counts)
#define W_SORTED 33024                // int[E]
#define F_XL     98560                // float[T][N][C]
#define F_H      (F_XL + T*NN*C)      // float[T][N][C]
#define F_SSRC   (F_H + T*NN*C)       // float[T][N]
#define F_SDST   (F_SSRC + T*NN)      // float[T][N]
#define F_SE     (F_SDST + T*NN)      // float[E]
#define F_SLOOP  (F_SE + EE)          // float[N*T] indexed n*T+t
#define F_WE     (F_SLOOP + T*NN)     // float[T][10] (padded 64)
#define F_HACC   (F_WE + 64)          // float[N][C]
#define F_WT     (F_HACC + NN*C)      // float[256][768] in_proj_w transposed
#define F_QKV    (F_WT + 768*256)     // float[N][768]
#define F_ONUM   (F_QKV + NN*768)     // float[N][C]
#define F_DENOM  (F_ONUM + NN*C)      // float[N][AH]
#define F_MEANP  (F_DENOM + NN*AHD)   // float[C]
#define F_MAXP   (F_MEANP + C)        // float[C]
#define F_OMEAN  (F_MAXP + C)         // float[C]
#define F_ATTNP  (F_OMEAN + C)        // float[C]
#define F_G1     (F_ATTNP + C)        // float[512]
#define WS_WORDS (F_G1 + 512)
#define NZERO (NN*C + NN*AHD + 3*C)   // o_num, denom, meanp, maxp, omean

static __device__ __forceinline__ float lrelu(float x){ return x > 0.f ? x : 0.2f*x; }
static __device__ __forceinline__ float eluf(float x){ return x > 0.f ? x : __expf(x) - 1.f; }

static __device__ inline void atomicMaxF(float* addr, float val){
  int* ai = (int*)addr;
  int old = __float_as_int(*addr);
  while (__int_as_float(old) < val){
    int assumed = old;
    old = atomicCAS(ai, assumed, __float_as_int(val));
    if (old == assumed) break;
  }
}

__global__ __launch_bounds__(256) void zero_k(float* fz, int nf, int* iz, int ni){
  int i = blockIdx.x*256 + threadIdx.x;
  if (i < nf) fz[i] = 0.f;
  if (i < ni) iz[i] = 0;
}
__global__ __launch_bounds__(256) void initmax_k(float* maxp){ maxp[threadIdx.x] = -1e30f; }

__global__ __launch_bounds__(256) void hist_k(const int* __restrict__ dst, const int* __restrict__ ety, int* cnt){
  int e = blockIdx.x*256 + threadIdx.x;
  if (e < EE) atomicAdd(&cnt[dst[e]*T + ety[e]], 1);
}

__global__ __launch_bounds__(1024) void scan_k(int* cnt, int* off, int* cursor){
  __shared__ int part[1024];
  int tid = threadIdx.x;
  int base = tid*16;
  int loc[16]; int s = 0;
  for (int i = 0; i < 16; i++){ loc[i] = cnt[base+i]; s += loc[i]; }
  part[tid] = s; __syncthreads();
  int v = s;
  for (int offn = 1; offn < 1024; offn <<= 1){
    int add = (tid >= offn) ? part[tid-offn] : 0;
    __syncthreads();
    v += add; part[tid] = v;
    __syncthreads();
  }
  int excl = v - s;
  for (int i = 0; i < 16; i++){ off[base+i] = excl; cursor[base+i] = excl; excl += loc[i]; }
  if (tid == 1023) off[NN*T] = excl;
}

__global__ __launch_bounds__(256) void scatter_k(const int* __restrict__ dst, const int* __restrict__ ety,
                                                 int* cursor, int* sorted){
  int e = blockIdx.x*256 + threadIdx.x;
  if (e < EE){
    int p = atomicAdd(&cursor[dst[e]*T + ety[e]], 1);
    sorted[p] = e;
  }
}

// we[t][k] = sum_c lin_edge_w[t,l,k,c] * att_edge[t,l,0,c]
__global__ __launch_bounds__(256) void we2_k(const float* __restrict__ linE, const float* __restrict__ attE,
                                             float* we, int l){
  int t = blockIdx.x, c = threadIdx.x;
  __shared__ float part[10*C];
  float ae = attE[(t*LL + l)*C + c];
  const float* lw = linE + (size_t)((t*LL + l)*10)*C;
  for (int k = 0; k < 10; k++) part[k*C + c] = lw[k*C + c]*ae;
  __syncthreads();
  if (c < 10){
    float s = 0.f;
    for (int i = 0; i < C; i++) s += part[c*C + i];
    we[t*10 + c] = s;
  }
}

// xl[t][n][:] = h_t[n][:] @ W_t ; 8 nodes per block
__global__ __launch_bounds__(256) void gemm_k(const float* __restrict__ hin, long htstr, int K,
                                              const float* __restrict__ Wb, long wtstr,
                                              float* __restrict__ xlo){
  int t = blockIdx.y;
  const float* h = hin + (size_t)t*htstr;
  const float* W = Wb + (size_t)t*wtstr;
  int n0 = blockIdx.x*8;
  __shared__ float sh[8*256];
  for (int j = 0; j < 8; j++)
    for (int k = threadIdx.x; k < K; k += 256)
      sh[j*K + k] = h[(n0+j)*K + k];
  __syncthreads();
  float acc[8] = {0,0,0,0,0,0,0,0};
  int c = threadIdx.x;
  for (int k = 0; k < K; k++){
    float w = W[k*C + c];
    #pragma unroll
    for (int j = 0; j < 8; j++) acc[j] += w * sh[j*K + k];
  }
  for (int j = 0; j < 8; j++) xlo[(t*NN + n0 + j)*C + c] = acc[j];
}

__global__ __launch_bounds__(256) void ssd_k(const float* __restrict__ xl, const float* __restrict__ attS,
                                             const float* __restrict__ attD, float* ssrc, float* sdst, int l){
  int n = blockIdx.x, t = blockIdx.y, c = threadIdx.x;
  __shared__ float r1[256], r2[256];
  float v = xl[(t*NN + n)*C + c];
  r1[c] = v * attS[(t*LL + l)*C + c];
  r2[c] = v * attD[(t*LL + l)*C + c];
  __syncthreads();
  for (int s = 128; s > 0; s >>= 1){
    if (c < s){ r1[c] += r1[c+s]; r2[c] += r2[c+s]; }
    __syncthreads();
  }
  if (c == 0){ ssrc[t*NN + n] = r1[0]; sdst[t*NN + n] = r2[0]; }
}

__global__ __launch_bounds__(256) void se_k(const float* __restrict__ eattr, const int* __restrict__ ety,
                                            const float* __restrict__ we, float* se){
  int e = blockIdx.x*256 + threadIdx.x;
  if (e < EE){
    const float* w = we + ety[e]*10;
    const float* ea = eattr + e*10;
    float s = 0.f;
    #pragma unroll
    for (int k = 0; k < 10; k++) s += ea[k]*w[k];
    se[e] = s;
  }
}

__global__ __launch_bounds__(256) void sloop_k(const int* __restrict__ off, const int* __restrict__ sorted,
                                               const float* __restrict__ se, float* sloop){
  int i = blockIdx.x*256 + threadIdx.x;
  if (i < NN*T){
    int o0 = off[i], o1 = off[i+1];
    float s = 0.f;
    for (int j = o0; j < o1; j++) s += se[sorted[j]];
    int dg = o1 - o0;
    sloop[i] = s / (float)(dg > 0 ? dg : 1);
  }
}

__global__ __launch_bounds__(256) void agg_k(const float* __restrict__ xl, const float* __restrict__ ssrc,
                                             const float* __restrict__ sdst, const float* __restrict__ se,
                                             const float* __restrict__ sloop, const int* __restrict__ off,
                                             const int* __restrict__ sorted, const int* __restrict__ srcv,
                                             const float* __restrict__ bias, float* __restrict__ hout, int l){
  int n = blockIdx.x, t = blockIdx.y;
  int i = n*T + t;
  int o0 = off[i];
  int deg = off[i+1] - o0;
  if (deg > 512) deg = 512;   // Poisson(4) tail: overflow probabilistically impossible
  __shared__ float sc[512];
  __shared__ int sj[512];
  __shared__ float sInv, sAL;
  for (int j = threadIdx.x; j < deg; j += 256){
    int e = sorted[o0 + j];
    int sn = srcv[e];
    sc[j] = lrelu(ssrc[t*NN + sn] + sdst[t*NN + n] + se[e]);
    sj[j] = sn;
  }
  __syncthreads();
  if (threadIdx.x == 0){
    float al = lrelu(ssrc[t*NN + n] + sdst[t*NN + n] + sloop[i]);
    float mx = al;
    for (int j = 0; j < deg; j++) mx = fmaxf(mx, sc[j]);
    float al_e = __expf(al - mx);
    float ssum = al_e;
    for (int j = 0; j < deg; j++){ float ex = __expf(sc[j] - mx); sc[j] = ex; ssum += ex; }
    sInv = 1.f/(ssum + 1e-16f);
    sAL = al_e;
  }
  __syncthreads();
  int c = threadIdx.x;
  float acc = sAL * xl[(t*NN + n)*C + c];
  for (int j = 0; j < deg; j++) acc += sc[j] * xl[(t*NN + sj[j])*C + c];
  acc = acc*sInv + bias[(t*LL + l)*C + c];
  hout[(t*NN + n)*C + c] = eluf(acc);
}

__global__ __launch_bounds__(256) void hacc_k(const float* __restrict__ h, const float* __restrict__ etw,
                                              float* __restrict__ hacc){
  int n = blockIdx.x, c = threadIdx.x;
  float e0 = etw[0], e1 = etw[1], e2 = etw[2], e3 = etw[3];
  float m = fmaxf(fmaxf(e0,e1), fmaxf(e2,e3));
  float w0 = __expf(e0-m), w1 = __expf(e1-m), w2 = __expf(e2-m), w3 = __expf(e3-m);
  float inv = 1.f/(w0+w1+w2+w3);
  float s = w0*h[(0*NN+n)*C+c] + w1*h[(1*NN+n)*C+c] + w2*h[(2*NN+n)*C+c] + w3*h[(3*NN+n)*C+c];
  hacc[n*C + c] = s*inv;
}

__global__ __launch_bounds__(256) void colstats_k(const float* __restrict__ hacc, float* meanp, float* maxp){
  int r0 = blockIdx.x*128, c = threadIdx.x;
  float sm = 0.f, mx = -1e30f;
  for (int r = 0; r < 128; r++){
    float v = hacc[(r0+r)*C + c];
    sm += v; mx = fmaxf(mx, v);
  }
  atomicAdd(&meanp[c], sm*(1.f/4096.f));
  atomicMaxF(&maxp[c], mx);
}

__global__ __launch_bounds__(256) void transpose_k(const float* __restrict__ ipw, float* __restrict__ WT){
  int i = blockIdx.x*256 + threadIdx.x;
  if (i < 768*256){
    int j = i >> 8, k = i & 255;
    WT[k*768 + j] = ipw[i];
  }
}

__global__ __launch_bounds__(256) void qkv_k(const float* __restrict__ hacc, const float* __restrict__ WT,
                                             const float* __restrict__ ipb, float* __restrict__ qkv){
  int p = blockIdx.y;
  int n0 = blockIdx.x*8;
  int jj = threadIdx.x;
  __shared__ float sh[8*256];
  for (int j = 0; j < 8; j++) sh[j*256 + threadIdx.x] = hacc[(n0+j)*C + threadIdx.x];
  __syncthreads();
  float acc[8] = {0,0,0,0,0,0,0,0};
  int col = p*256 + jj;
  for (int k = 0; k < 256; k++){
    float w = WT[k*768 + col];
    #pragma unroll
    for (int j = 0; j < 8; j++) acc[j] += w * sh[j*256 + k];
  }
  float b = ipb[col];
  for (int j = 0; j < 8; j++) qkv[(n0+j)*768 + col] = acc[j] + b;
}

// thread = one (head, n); m-chunked, max-free softmax partials (scores bounded, |s| << 80)
__global__ __launch_bounds__(256) void attn_k(const float* __restrict__ qkv, float* __restrict__ onum,
                                              float* __restrict__ denom){
  int n = blockIdx.x*256 + threadIdx.x;
  int head = blockIdx.y;
  int mc = blockIdx.z;
  float q[64], o[64];
  const float* qrow = qkv + (size_t)n*768 + head*64;
  #pragma unroll
  for (int d = 0; d < 64; d++){ q[d] = qrow[d]; o[d] = 0.f; }
  float ssum = 0.f;
  int m0 = mc*512;
  for (int m = m0; m < m0 + 512; m++){
    const float* kr = qkv + (size_t)m*768 + 256 + head*64;
    float s = 0.f;
    #pragma unroll
    for (int d = 0; d < 64; d++) s += q[d]*kr[d];
    float p = __expf(s*0.125f);
    ssum += p;
    const float* vr = kr + 256;
    #pragma unroll
    for (int d = 0; d < 64; d++) o[d] += p*vr[d];
  }
  #pragma unroll
  for (int d = 0; d < 64; d++) atomicAdd(&onum[n*C + head*64 + d], o[d]);
  atomicAdd(&denom[n*AHD + head], ssum);
}

__global__ __launch_bounds__(256) void attnred_k(const float* __restrict__ onum, const float* __restrict__ denom,
                                                 float* omean){
  int r0 = blockIdx.x*128, c = threadIdx.x;
  float s = 0.f;
  for (int r = 0; r < 128; r++){
    int n = r0 + r;
    s += onum[n*C + c] / denom[n*AHD + (c >> 6)];
  }
  atomicAdd(&omean[c], s*(1.f/4096.f));
}

__global__ __launch_bounds__(256) void attnproj_k(const float* __restrict__ omean, const float* __restrict__ opw,
                                                  const float* __restrict__ opb, float* attnp){
  __shared__ float sh[256];
  int j = threadIdx.x;
  sh[j] = omean[j];
  __syncthreads();
  float acc = opb[j];
  for (int k = 0; k < 256; k++) acc += sh[k]*opw[j*256 + k];
  attnp[j] = acc;
}

__global__ __launch_bounds__(512) void fus1_k(const float* __restrict__ meanp, const float* __restrict__ maxp,
                                              const float* __restrict__ attnp, const float* __restrict__ fw1,
                                              const float* __restrict__ fb1, float* g1){
  __shared__ float comb[768];
  for (int i = threadIdx.x; i < 768; i += 512)
    comb[i] = (i < 256) ? meanp[i] : (i < 512 ? maxp[i-256] : attnp[i-512]);
  __syncthreads();
  int j = threadIdx.x;
  float acc = fb1[j];
  for (int k = 0; k < 768; k++) acc += comb[k]*fw1[k*512 + j];
  g1[j] = fmaxf(acc, 0.f);
}

__global__ __launch_bounds__(256) void fus2_k(const float* __restrict__ g1, const float* __restrict__ fw2,
                                              const float* __restrict__ fb2, float* __restrict__ out){
  __shared__ float g[512];
  g[threadIdx.x] = g1[threadIdx.x];
  g[threadIdx.x + 256] = g1[threadIdx.x + 256];
  __syncthreads();
  int j = threadIdx.x;
  float acc = fb2[j];
  for (int k = 0; k < 512; k++) acc += g[k]*fw2[k*256 + j];
  out[j] = fmaxf(acc, 0.f);
}

extern "C" void kernel_launch(void* const* d_in, const int* in_sizes, int n_in,
                              void* d_out, int out_size, void* d_ws, size_t ws_size,
                              hipStream_t stream){
  const float* x     = (const float*)d_in[0];
  const int*   srcv  = (const int*)d_in[1];
  const int*   dstv  = (const int*)d_in[2];
  const float* eattr = (const float*)d_in[3];
  const int*   etyp  = (const int*)d_in[4];
  const float* W0    = (const float*)d_in[5];
  const float* W12   = (const float*)d_in[6];
  const float* attS  = (const float*)d_in[7];
  const float* attD  = (const float*)d_in[8];
  const float* attE  = (const float*)d_in[9];
  const float* linE  = (const float*)d_in[10];
  const float* bias  = (const float*)d_in[11];
  const float* etw   = (const float*)d_in[12];
  const float* ipw   = (const float*)d_in[13];
  const float* ipb   = (const float*)d_in[14];
  const float* opw   = (const float*)d_in[15];
  const float* opb   = (const float*)d_in[16];
  const float* fw1   = (const float*)d_in[17];
  const float* fb1   = (const float*)d_in[18];
  const float* fw2   = (const float*)d_in[19];
  const float* fb2   = (const float*)d_in[20];
  float* out = (float*)d_out;

  if (ws_size < (size_t)WS_WORDS*4) return;  // insufficient scratch -> fail loudly

  int*   ip = (int*)d_ws;
  float* fp = (float*)d_ws;

  zero_k<<<(NZERO + 255)/256, 256, 0, stream>>>(fp + F_ONUM, NZERO, ip + W_CURSOR, NN*T);
  initmax_k<<<1, 256, 0, stream>>>(fp + F_MAXP);

  hist_k<<<EE/256, 256, 0, stream>>>(dstv, etyp, ip + W_CURSOR);
  scan_k<<<1, 1024, 0, stream>>>(ip + W_CURSOR, ip + W_OFF, ip + W_CURSOR);
  scatter_k<<<EE/256, 256, 0, stream>>>(dstv, etyp, ip + W_CURSOR, ip + W_SORTED);

  transpose_k<<<768, 256, 0, stream>>>(ipw, fp + F_WT);

  for (int l = 0; l < 3; l++){
    const float* hin = (l == 0) ? x : (fp + F_H);
    long htstr = (l == 0) ? 0 : (long)NN*C;
    int K = (l == 0) ? DIN : C;
    const float* Wb = (l == 0) ? W0 : (W12 + (size_t)(l-1)*C*C);
    long wtstr = (l == 0) ? (long)DIN*C : (long)2*C*C;

    gemm_k<<<dim3(NN/8, T), 256, 0, stream>>>(hin, htstr, K, Wb, wtstr, fp + F_XL);
    ssd_k<<<dim3(NN, T), 256, 0, stream>>>(fp + F_XL, attS, attD, fp + F_SSRC, fp + F_SDST, l);
    we2_k<<<T, 256, 0, stream>>>(linE, attE, fp + F_WE, l);
    se_k<<<EE/256, 256, 0, stream>>>(eattr, etyp, fp + F_WE, fp + F_SE);
    sloop_k<<<(NN*T)/256, 256, 0, stream>>>(ip + W_OFF, ip + W_SORTED, fp + F_SE, fp + F_SLOOP);
    agg_k<<<dim3(NN, T), 256, 0, stream>>>(fp + F_XL, fp + F_SSRC, fp + F_SDST, fp + F_SE,
                                           fp + F_SLOOP, ip + W_OFF, ip + W_SORTED, srcv,
                                           bias, fp + F_H, l);
  }

  hacc_k<<<NN, 256, 0, stream>>>(fp + F_H, etw, fp + F_HACC);
  colstats_k<<<32, 256, 0, stream>>>(fp + F_HACC, fp + F_MEANP, fp + F_MAXP);

  qkv_k<<<dim3(NN/8, 3), 256, 0, stream>>>(fp + F_HACC, fp + F_WT, ipb, fp + F_QKV);
  attn_k<<<dim3(16, AHD, 8), 256, 0, stream>>>(fp + F_QKV, fp + F_ONUM, fp + F_DENOM);
  attnred_k<<<32, 256, 0, stream>>>(fp + F_ONUM, fp + F_DENOM, fp + F_OMEAN);
  attnproj_k<<<1, 256, 0, stream>>>(fp + F_OMEAN, opw, opb, fp + F_ATTNP);

  fus1_k<<<1, 512, 0, stream>>>(fp + F_MEANP, fp + F_MAXP, fp + F_ATTNP, fw1, fb1, fp + F_G1);
  fus2_k<<<1, 256, 0, stream>>>(fp + F_G1, fw2, fb2, out);
}

// Round 2
// 1324.978 us; speedup vs baseline: 1.0020x; 1.0020x over previous
//
#include <hip/hip_runtime.h>
#include <math.h>

#define T 4
#define LL 3
#define C 256
#define DIN 20
#define NN 4096
#define EE 65536
#define AHD 4

// ---- workspace layout (4-byte word offsets) ----
#define W_OFF    0                    // int[N*T+1]
#define W_CURSOR 16640                // int[N*T]  (also hist counts)
#define W_SORTED 33024                // int[E]
#define F_XL     98560                // float[T][N][C]
#define F_H      (F_XL + T*NN*C)      // float[T][N][C]
#define F_SSRC   (F_H + T*NN*C)       // float[T][N]
#define F_SDST   (F_SSRC + T*NN)      // float[T][N]
#define F_SE     (F_SDST + T*NN)      // float[E]
#define F_SLOOP  (F_SE + EE)          // float[N*T] indexed n*T+t
#define F_WE     (F_SLOOP + T*NN)     // float[T][10] (padded 64)
#define F_HACC   (F_WE + 64)          // float[N][C]
#define F_WT     (F_HACC + NN*C)      // float[256][768] in_proj_w transposed
#define F_QKV    (F_WT + 768*256)     // float[N][768]
#define F_ONUM   (F_QKV + NN*768)     // float[N][C]
#define F_DENOM  (F_ONUM + NN*C)      // float[N][AH]
#define F_MEANP  (F_DENOM + NN*AHD)   // float[C]
#define F_MAXP   (F_MEANP + C)        // float[C]
#define F_OMEAN  (F_MAXP + C)         // float[C]
#define F_ATTNP  (F_OMEAN + C)        // float[C]
#define F_G1     (F_ATTNP + C)        // float[512]
#define WS_WORDS (F_G1 + 512)
#define NZERO (NN*C + NN*AHD + 3*C)   // o_num, denom, meanp, maxp, omean

static __device__ __forceinline__ float lrelu(float x){ return x > 0.f ? x : 0.2f*x; }
static __device__ __forceinline__ float eluf(float x){ return x > 0.f ? x : __expf(x) - 1.f; }

static __device__ inline void atomicMaxF(float* addr, float val){
  int* ai = (int*)addr;
  int old = __float_as_int(*addr);
  while (__int_as_float(old) < val){
    int assumed = old;
    old = atomicCAS(ai, assumed, __float_as_int(val));
    if (old == assumed) break;
  }
}

__global__ __launch_bounds__(256) void zero_k(float* fz, int nf, int* iz, int ni){
  int i = blockIdx.x*256 + threadIdx.x;
  if (i < nf) fz[i] = 0.f;
  if (i < ni) iz[i] = 0;
}
__global__ __launch_bounds__(256) void initmax_k(float* maxp){ maxp[threadIdx.x] = -1e30f; }

__global__ __launch_bounds__(256) void hist_k(const int* __restrict__ dst, const int* __restrict__ ety, int* cnt){
  int e = blockIdx.x*256 + threadIdx.x;
  if (e < EE) atomicAdd(&cnt[dst[e]*T + ety[e]], 1);
}

__global__ __launch_bounds__(1024) void scan_k(int* cnt, int* off, int* cursor){
  __shared__ int part[1024];
  int tid = threadIdx.x;
  int base = tid*16;
  int loc[16]; int s = 0;
  for (int i = 0; i < 16; i++){ loc[i] = cnt[base+i]; s += loc[i]; }
  part[tid] = s; __syncthreads();
  int v = s;
  for (int offn = 1; offn < 1024; offn <<= 1){
    int add = (tid >= offn) ? part[tid-offn] : 0;
    __syncthreads();
    v += add; part[tid] = v;
    __syncthreads();
  }
  int excl = v - s;
  for (int i = 0; i < 16; i++){ off[base+i] = excl; cursor[base+i] = excl; excl += loc[i]; }
  if (tid == 1023) off[NN*T] = excl;
}

__global__ __launch_bounds__(256) void scatter_k(const int* __restrict__ dst, const int* __restrict__ ety,
                                                 int* cursor, int* sorted){
  int e = blockIdx.x*256 + threadIdx.x;
  if (e < EE){
    int p = atomicAdd(&cursor[dst[e]*T + ety[e]], 1);
    sorted[p] = e;
  }
}

// we[t][k] = sum_c lin_edge_w[t,l,k,c] * att_edge[t,l,0,c]
__global__ __launch_bounds__(256) void we2_k(const float* __restrict__ linE, const float* __restrict__ attE,
                                             float* we, int l){
  int t = blockIdx.x, c = threadIdx.x;
  __shared__ float part[10*C];
  float ae = attE[(t*LL + l)*C + c];
  const float* lw = linE + (size_t)((t*LL + l)*10)*C;
  for (int k = 0; k < 10; k++) part[k*C + c] = lw[k*C + c]*ae;
  __syncthreads();
  if (c < 10){
    float s = 0.f;
    for (int i = 0; i < C; i++) s += part[c*C + i];
    we[t*10 + c] = s;
  }
}

// xl[t][n][:] = h_t[n][:] @ W_t ; 8 nodes per block
__global__ __launch_bounds__(256) void gemm_k(const float* __restrict__ hin, long htstr, int K,
                                              const float* __restrict__ Wb, long wtstr,
                                              float* __restrict__ xlo){
  int t = blockIdx.y;
  const float* h = hin + (size_t)t*htstr;
  const float* W = Wb + (size_t)t*wtstr;
  int n0 = blockIdx.x*8;
  __shared__ float sh[8*256];
  for (int j = 0; j < 8; j++)
    for (int k = threadIdx.x; k < K; k += 256)
      sh[j*K + k] = h[(n0+j)*K + k];
  __syncthreads();
  float acc[8] = {0,0,0,0,0,0,0,0};
  int c = threadIdx.x;
  for (int k = 0; k < K; k++){
    float w = W[k*C + c];
    #pragma unroll
    for (int j = 0; j < 8; j++) acc[j] += w * sh[j*K + k];
  }
  for (int j = 0; j < 8; j++) xlo[(t*NN + n0 + j)*C + c] = acc[j];
}

__global__ __launch_bounds__(256) void ssd_k(const float* __restrict__ xl, const float* __restrict__ attS,
                                             const float* __restrict__ attD, float* ssrc, float* sdst, int l){
  int n = blockIdx.x, t = blockIdx.y, c = threadIdx.x;
  __shared__ float r1[256], r2[256];
  float v = xl[(t*NN + n)*C + c];
  r1[c] = v * attS[(t*LL + l)*C + c];
  r2[c] = v * attD[(t*LL + l)*C + c];
  __syncthreads();
  for (int s = 128; s > 0; s >>= 1){
    if (c < s){ r1[c] += r1[c+s]; r2[c] += r2[c+s]; }
    __syncthreads();
  }
  if (c == 0){ ssrc[t*NN + n] = r1[0]; sdst[t*NN + n] = r2[0]; }
}

__global__ __launch_bounds__(256) void se_k(const float* __restrict__ eattr, const int* __restrict__ ety,
                                            const float* __restrict__ we, float* se){
  int e = blockIdx.x*256 + threadIdx.x;
  if (e < EE){
    const float* w = we + ety[e]*10;
    const float* ea = eattr + e*10;
    float s = 0.f;
    #pragma unroll
    for (int k = 0; k < 10; k++) s += ea[k]*w[k];
    se[e] = s;
  }
}

__global__ __launch_bounds__(256) void sloop_k(const int* __restrict__ off, const int* __restrict__ sorted,
                                               const float* __restrict__ se, float* sloop){
  int i = blockIdx.x*256 + threadIdx.x;
  if (i < NN*T){
    int o0 = off[i], o1 = off[i+1];
    float s = 0.f;
    for (int j = o0; j < o1; j++) s += se[sorted[j]];
    int dg = o1 - o0;
    sloop[i] = s / (float)(dg > 0 ? dg : 1);
  }
}

__global__ __launch_bounds__(256) void agg_k(const float* __restrict__ xl, const float* __restrict__ ssrc,
                                             const float* __restrict__ sdst, const float* __restrict__ se,
                                             const float* __restrict__ sloop, const int* __restrict__ off,
                                             const int* __restrict__ sorted, const int* __restrict__ srcv,
                                             const float* __restrict__ bias, float* __restrict__ hout, int l){
  int n = blockIdx.x, t = blockIdx.y;
  int i = n*T + t;
  int o0 = off[i];
  int deg = off[i+1] - o0;
  if (deg > 512) deg = 512;   // Poisson(4) tail: overflow probabilistically impossible
  __shared__ float sc[512];
  __shared__ int sj[512];
  __shared__ float sInv, sAL;
  for (int j = threadIdx.x; j < deg; j += 256){
    int e = sorted[o0 + j];
    int sn = srcv[e];
    sc[j] = lrelu(ssrc[t*NN + sn] + sdst[t*NN + n] + se[e]);
    sj[j] = sn;
  }
  __syncthreads();
  if (threadIdx.x == 0){
    float al = lrelu(ssrc[t*NN + n] + sdst[t*NN + n] + sloop[i]);
    float mx = al;
    for (int j = 0; j < deg; j++) mx = fmaxf(mx, sc[j]);
    float al_e = __expf(al - mx);
    float ssum = al_e;
    for (int j = 0; j < deg; j++){ float ex = __expf(sc[j] - mx); sc[j] = ex; ssum += ex; }
    sInv = 1.f/(ssum + 1e-16f);
    sAL = al_e;
  }
  __syncthreads();
  int c = threadIdx.x;
  float acc = sAL * xl[(t*NN + n)*C + c];
  for (int j = 0; j < deg; j++) acc += sc[j] * xl[(t*NN + sj[j])*C + c];
  acc = acc*sInv + bias[(t*LL + l)*C + c];
  hout[(t*NN + n)*C + c] = eluf(acc);
}

__global__ __launch_bounds__(256) void hacc_k(const float* __restrict__ h, const float* __restrict__ etw,
                                              float* __restrict__ hacc){
  int n = blockIdx.x, c = threadIdx.x;
  float e0 = etw[0], e1 = etw[1], e2 = etw[2], e3 = etw[3];
  float m = fmaxf(fmaxf(e0,e1), fmaxf(e2,e3));
  float w0 = __expf(e0-m), w1 = __expf(e1-m), w2 = __expf(e2-m), w3 = __expf(e3-m);
  float inv = 1.f/(w0+w1+w2+w3);
  float s = w0*h[(0*NN+n)*C+c] + w1*h[(1*NN+n)*C+c] + w2*h[(2*NN+n)*C+c] + w3*h[(3*NN+n)*C+c];
  hacc[n*C + c] = s*inv;
}

__global__ __launch_bounds__(256) void colstats_k(const float* __restrict__ hacc, float* meanp, float* maxp){
  int r0 = blockIdx.x*128, c = threadIdx.x;
  float sm = 0.f, mx = -1e30f;
  for (int r = 0; r < 128; r++){
    float v = hacc[(r0+r)*C + c];
    sm += v; mx = fmaxf(mx, v);
  }
  atomicAdd(&meanp[c], sm*(1.f/4096.f));
  atomicMaxF(&maxp[c], mx);
}

__global__ __launch_bounds__(256) void transpose_k(const float* __restrict__ ipw, float* __restrict__ WT){
  int i = blockIdx.x*256 + threadIdx.x;
  if (i < 768*256){
    int j = i >> 8, k = i & 255;
    WT[k*768 + j] = ipw[i];
  }
}

__global__ __launch_bounds__(256) void qkv_k(const float* __restrict__ hacc, const float* __restrict__ WT,
                                             const float* __restrict__ ipb, float* __restrict__ qkv){
  int p = blockIdx.y;
  int n0 = blockIdx.x*8;
  int jj = threadIdx.x;
  __shared__ float sh[8*256];
  for (int j = 0; j < 8; j++) sh[j*256 + threadIdx.x] = hacc[(n0+j)*C + threadIdx.x];
  __syncthreads();
  float acc[8] = {0,0,0,0,0,0,0,0};
  int col = p*256 + jj;
  for (int k = 0; k < 256; k++){
    float w = WT[k*768 + col];
    #pragma unroll
    for (int j = 0; j < 8; j++) acc[j] += w * sh[j*256 + k];
  }
  float b = ipb[col];
  for (int j = 0; j < 8; j++) qkv[(n0+j)*768 + col] = acc[j] + b;
}

// thread = one (head, n); m-chunked, max-free softmax partials (scores bounded, |s| << 80).
// __launch_bounds__(256,2): VGPR cap 256 so q[16]+o[16] float4 arrays stay in registers
// (R1 post-mortem: default occupancy target spilled both arrays -> 264 MB scratch traffic).
__global__ __launch_bounds__(256, 2) void attn_k(const float* __restrict__ qkv, float* __restrict__ onum,
                                                 float* __restrict__ denom){
  int n = blockIdx.x*256 + threadIdx.x;
  int head = blockIdx.y;
  int mc = blockIdx.z;
  float4 q[16], o[16];
  const float4* qrow = (const float4*)(qkv + (size_t)n*768 + head*64);
  #pragma unroll
  for (int i = 0; i < 16; i++){ q[i] = qrow[i]; o[i] = make_float4(0.f,0.f,0.f,0.f); }
  float ssum = 0.f;
  const float* kbase = qkv + 256 + head*64 + (size_t)(mc*512)*768;
  for (int m = 0; m < 512; m++){
    const float4* kr = (const float4*)(kbase + (size_t)m*768);   // wave-uniform address
    float s0 = 0.f, s1 = 0.f, s2 = 0.f, s3 = 0.f;
    #pragma unroll
    for (int i = 0; i < 16; i += 4){
      float4 k0 = kr[i], k1 = kr[i+1], k2 = kr[i+2], k3 = kr[i+3];
      s0 += q[i  ].x*k0.x + q[i  ].y*k0.y + q[i  ].z*k0.z + q[i  ].w*k0.w;
      s1 += q[i+1].x*k1.x + q[i+1].y*k1.y + q[i+1].z*k1.z + q[i+1].w*k1.w;
      s2 += q[i+2].x*k2.x + q[i+2].y*k2.y + q[i+2].z*k2.z + q[i+2].w*k2.w;
      s3 += q[i+3].x*k3.x + q[i+3].y*k3.y + q[i+3].z*k3.z + q[i+3].w*k3.w;
    }
    float p = __expf((s0+s1+s2+s3)*0.125f);
    ssum += p;
    const float4* vr = kr + 64;   // v sits 256 floats after k in the qkv row
    #pragma unroll
    for (int i = 0; i < 16; i++){
      float4 v4 = vr[i];
      o[i].x += p*v4.x; o[i].y += p*v4.y; o[i].z += p*v4.z; o[i].w += p*v4.w;
    }
  }
  float* ob = onum + (size_t)n*C + head*64;
  #pragma unroll
  for (int i = 0; i < 16; i++){
    atomicAdd(&ob[4*i+0], o[i].x); atomicAdd(&ob[4*i+1], o[i].y);
    atomicAdd(&ob[4*i+2], o[i].z); atomicAdd(&ob[4*i+3], o[i].w);
  }
  atomicAdd(&denom[n*AHD + head], ssum);
}

__global__ __launch_bounds__(256) void attnred_k(const float* __restrict__ onum, const float* __restrict__ denom,
                                                 float* omean){
  int r0 = blockIdx.x*128, c = threadIdx.x;
  float s = 0.f;
  for (int r = 0; r < 128; r++){
    int n = r0 + r;
    s += onum[n*C + c] / denom[n*AHD + (c >> 6)];
  }
  atomicAdd(&omean[c], s*(1.f/4096.f));
}

__global__ __launch_bounds__(256) void attnproj_k(const float* __restrict__ omean, const float* __restrict__ opw,
                                                  const float* __restrict__ opb, float* attnp){
  __shared__ float sh[256];
  int j = threadIdx.x;
  sh[j] = omean[j];
  __syncthreads();
  float acc = opb[j];
  for (int k = 0; k < 256; k++) acc += sh[k]*opw[j*256 + k];
  attnp[j] = acc;
}

__global__ __launch_bounds__(512) void fus1_k(const float* __restrict__ meanp, const float* __restrict__ maxp,
                                              const float* __restrict__ attnp, const float* __restrict__ fw1,
                                              const float* __restrict__ fb1, float* g1){
  __shared__ float comb[768];
  for (int i = threadIdx.x; i < 768; i += 512)
    comb[i] = (i < 256) ? meanp[i] : (i < 512 ? maxp[i-256] : attnp[i-512]);
  __syncthreads();
  int j = threadIdx.x;
  float acc = fb1[j];
  for (int k = 0; k < 768; k++) acc += comb[k]*fw1[k*512 + j];
  g1[j] = fmaxf(acc, 0.f);
}

__global__ __launch_bounds__(256) void fus2_k(const float* __restrict__ g1, const float* __restrict__ fw2,
                                              const float* __restrict__ fb2, float* __restrict__ out){
  __shared__ float g[512];
  g[threadIdx.x] = g1[threadIdx.x];
  g[threadIdx.x + 256] = g1[threadIdx.x + 256];
  __syncthreads();
  int j = threadIdx.x;
  float acc = fb2[j];
  for (int k = 0; k < 512; k++) acc += g[k]*fw2[k*256 + j];
  out[j] = fmaxf(acc, 0.f);
}

extern "C" void kernel_launch(void* const* d_in, const int* in_sizes, int n_in,
                              void* d_out, int out_size, void* d_ws, size_t ws_size,
                              hipStream_t stream){
  const float* x     = (const float*)d_in[0];
  const int*   srcv  = (const int*)d_in[1];
  const int*   dstv  = (const int*)d_in[2];
  const float* eattr = (const float*)d_in[3];
  const int*   etyp  = (const int*)d_in[4];
  const float* W0    = (const float*)d_in[5];
  const float* W12   = (const float*)d_in[6];
  const float* attS  = (const float*)d_in[7];
  const float* attD  = (const float*)d_in[8];
  const float* attE  = (const float*)d_in[9];
  const float* linE  = (const float*)d_in[10];
  const float* bias  = (const float*)d_in[11];
  const float* etw   = (const float*)d_in[12];
  const float* ipw   = (const float*)d_in[13];
  const float* ipb   = (const float*)d_in[14];
  const float* opw   = (const float*)d_in[15];
  const float* opb   = (const float*)d_in[16];
  const float* fw1   = (const float*)d_in[17];
  const float* fb1   = (const float*)d_in[18];
  const float* fw2   = (const float*)d_in[19];
  const float* fb2   = (const float*)d_in[20];
  float* out = (float*)d_out;

  if (ws_size < (size_t)WS_WORDS*4) return;  // insufficient scratch -> fail loudly

  int*   ip = (int*)d_ws;
  float* fp = (float*)d_ws;

  zero_k<<<(NZERO + 255)/256, 256, 0, stream>>>(fp + F_ONUM, NZERO, ip + W_CURSOR, NN*T);
  initmax_k<<<1, 256, 0, stream>>>(fp + F_MAXP);

  hist_k<<<EE/256, 256, 0, stream>>>(dstv, etyp, ip + W_CURSOR);
  scan_k<<<1, 1024, 0, stream>>>(ip + W_CURSOR, ip + W_OFF, ip + W_CURSOR);
  scatter_k<<<EE/256, 256, 0, stream>>>(dstv, etyp, ip + W_CURSOR, ip + W_SORTED);

  transpose_k<<<768, 256, 0, stream>>>(ipw, fp + F_WT);

  for (int l = 0; l < 3; l++){
    const float* hin = (l == 0) ? x : (fp + F_H);
    long htstr = (l == 0) ? 0 : (long)NN*C;
    int K = (l == 0) ? DIN : C;
    const float* Wb = (l == 0) ? W0 : (W12 + (size_t)(l-1)*C*C);
    long wtstr = (l == 0) ? (long)DIN*C : (long)2*C*C;

    gemm_k<<<dim3(NN/8, T), 256, 0, stream>>>(hin, htstr, K, Wb, wtstr, fp + F_XL);
    ssd_k<<<dim3(NN, T), 256, 0, stream>>>(fp + F_XL, attS, attD, fp + F_SSRC, fp + F_SDST, l);
    we2_k<<<T, 256, 0, stream>>>(linE, attE, fp + F_WE, l);
    se_k<<<EE/256, 256, 0, stream>>>(eattr, etyp, fp + F_WE, fp + F_SE);
    sloop_k<<<(NN*T)/256, 256, 0, stream>>>(ip + W_OFF, ip + W_SORTED, fp + F_SE, fp + F_SLOOP);
    agg_k<<<dim3(NN, T), 256, 0, stream>>>(fp + F_XL, fp + F_SSRC, fp + F_SDST, fp + F_SE,
                                           fp + F_SLOOP, ip + W_OFF, ip + W_SORTED, srcv,
                                           bias, fp + F_H, l);
  }

  hacc_k<<<NN, 256, 0, stream>>>(fp + F_H, etw, fp + F_HACC);
  colstats_k<<<32, 256, 0, stream>>>(fp + F_HACC, fp + F_MEANP, fp + F_MAXP);

  qkv_k<<<dim3(NN/8, 3), 256, 0, stream>>>(fp + F_HACC, fp + F_WT, ipb, fp + F_QKV);
  attn_k<<<dim3(16, AHD, 8), 256, 0, stream>>>(fp + F_QKV, fp + F_ONUM, fp + F_DENOM);
  attnred_k<<<32, 256, 0, stream>>>(fp + F_ONUM, fp + F_DENOM, fp + F_OMEAN);
  attnproj_k<<<1, 256, 0, stream>>>(fp + F_OMEAN, opw, opb, fp + F_ATTNP);

  fus1_k<<<1, 512, 0, stream>>>(fp + F_MEANP, fp + F_MAXP, fp + F_ATTNP, fw1, fb1, fp + F_G1);
  fus2_k<<<1, 256, 0, stream>>>(fp + F_G1, fw2, fb2, out);
}